// Round 7
// baseline (26.253 us; speedup 1.0000x reference)
//
#include <hip/hip_runtime.h>
#include <hip/hip_bf16.h>

// MaskedDenseLayer round 7: round-6 two-pass, but the precompute is rebuilt
// so every global read is block-contiguous (64KB sequential float4 streams,
// the same pattern the 6.8TB/s harness fills use). The bit/bf16 transposes
// happen entirely in registers (a thread keeps 16 rows x its 4 cols), so the
// pre kernel has ZERO LDS and ZERO strided reads.
//
// Pass 1 (made_pre7), grid 1321 x 256:
//   [0,784)    mask->bits:  block=(s, c of 49 k16-chunks), reads 64KB seq,
//              writes 2KB of transposed bit-bytes ([s][ot][q][t][lane] u8).
//   [784,833)  kern->bf16 step-major: block=c, reads 64KB seq, writes 8KB.
//   [833,1225) x -> bf16 [512][784].
//   [1225,1321) zero the pad bit-bytes (q>=1, t==12) -> B==0 exactly.
// Pass 2 (made_main7): identical to round 6's main kernel.

#define IN_DIM 784
#define OUT_DIM 1024
#define BS 512

typedef __attribute__((ext_vector_type(8))) short bf16x8;
typedef __attribute__((ext_vector_type(16))) float f32x16;

#define XT_OFF 0u            // bf16 [512][784]
#define KQ_OFF (1u << 20)    // 16B slots [32 ot][4 q][13 t][64 lane]
#define MB_OFF (3u << 20)    // u8 [16 s][32 ot][4 q][13 t][64 lane]

#define NMASK_BLOCKS 784     // 16 s * 49 c
#define NKERN_BLOCKS 49
#define NXT_BLOCKS   392     // 100352 float4 / 256
#define NPAD_BLOCKS  96      // 24576 u32 / 256

static __device__ inline short f2bf(float f) {
    __hip_bfloat16 h = __float2bfloat16(f);   // RNE
    short r; __builtin_memcpy(&r, &h, 2); return r;
}

static __device__ inline void c_to_qt(int c, int& q, int& t) {
    if (c < 13) { q = 0; t = c; }
    else        { q = 1 + (c - 13) / 12; t = (c - 13) % 12; }
}

__global__ __launch_bounds__(256) void made_pre7(
    const float* __restrict__ x,      // [512, 784]
    const float* __restrict__ masks,  // [16, 784, 1024]
    const float* __restrict__ kern,   // [784, 1024]
    unsigned char* __restrict__ ws)
{
    const int bid = blockIdx.x, tid = threadIdx.x;

    if (bid < NMASK_BLOCKS) {
        // ---- masks -> transposed bit-bytes; 64KB contiguous read ----
        const int s = bid / 49, c = bid % 49;
        const float4* mrow =
            (const float4*)(masks + ((size_t)s * IN_DIM + c * 16) * OUT_DIM) + tid;
        unsigned nib[16];
#pragma unroll
        for (int r = 0; r < 16; ++r) {
            float4 v = mrow[r * 256];
            nib[r] = (v.x != 0.f ? 1u : 0u) | (v.y != 0.f ? 2u : 0u)
                   | (v.z != 0.f ? 4u : 0u) | (v.w != 0.f ? 8u : 0u);
        }
        int q, t; c_to_qt(c, q, t);
        const int ot = tid >> 3;
        const size_t base32 =
            ((((size_t)(s * 32 + ot) * 4 + q) * 13 + t) * 16);   // u32 units
        unsigned* mb = (unsigned*)(ws + MB_OFF);
#pragma unroll
        for (int khl = 0; khl < 2; ++khl) {
            unsigned wd = 0;
#pragma unroll
            for (int j = 0; j < 4; ++j) {
                unsigned by = 0;
#pragma unroll
                for (int e = 0; e < 8; ++e)
                    by |= ((nib[khl * 8 + e] >> j) & 1u) << e;
                wd |= by << (8 * j);
            }
            mb[base32 + khl * 8 + (tid & 7)] = wd;
        }
    } else if (bid < NMASK_BLOCKS + NKERN_BLOCKS) {
        // ---- kern -> bf16 step-major; 64KB contiguous read ----
        const int c = bid - NMASK_BLOCKS;
        const float4* krow = (const float4*)(kern + (size_t)c * 16 * OUT_DIM) + tid;
        unsigned short ku[16][4];
#pragma unroll
        for (int r = 0; r < 16; ++r) {
            float4 v = krow[r * 256];
            ku[r][0] = (unsigned short)f2bf(v.x);
            ku[r][1] = (unsigned short)f2bf(v.y);
            ku[r][2] = (unsigned short)f2bf(v.z);
            ku[r][3] = (unsigned short)f2bf(v.w);
        }
        int q, t; c_to_qt(c, q, t);
        const int ot = tid >> 3;
        uint4* kq = (uint4*)(ws + KQ_OFF) + ((size_t)(ot * 4 + q) * 13 + t) * 64;
#pragma unroll
        for (int khl = 0; khl < 2; ++khl)
#pragma unroll
            for (int j = 0; j < 4; ++j) {
                uint4 slot;
                slot.x = (unsigned)ku[khl*8+0][j] | ((unsigned)ku[khl*8+1][j] << 16);
                slot.y = (unsigned)ku[khl*8+2][j] | ((unsigned)ku[khl*8+3][j] << 16);
                slot.z = (unsigned)ku[khl*8+4][j] | ((unsigned)ku[khl*8+5][j] << 16);
                slot.w = (unsigned)ku[khl*8+6][j] | ((unsigned)ku[khl*8+7][j] << 16);
                kq[khl * 32 + (tid & 7) * 4 + j] = slot;
            }
    } else if (bid < NMASK_BLOCKS + NKERN_BLOCKS + NXT_BLOCKS) {
        // ---- x -> bf16 ----
        const int i = (bid - NMASK_BLOCKS - NKERN_BLOCKS) * 256 + tid;
        float4 v = ((const float4*)x)[i];
        ushort4 o;
        o.x = (unsigned short)f2bf(v.x);
        o.y = (unsigned short)f2bf(v.y);
        o.z = (unsigned short)f2bf(v.z);
        o.w = (unsigned short)f2bf(v.w);
        ((ushort4*)(ws + XT_OFF))[i] = o;
    } else {
        // ---- zero pad bit-bytes: (s,ot), q in {1,2,3}, t==12 ----
        const int g   = (bid - NMASK_BLOCKS - NKERN_BLOCKS - NXT_BLOCKS) * 256 + tid;
        const int run = g >> 4, off = g & 15;
        const int sot = run / 3, q = run % 3 + 1;
        ((unsigned*)(ws + MB_OFF))[((size_t)(sot * 4 + q) * 13 + 12) * 16 + off] = 0u;
    }
}

__global__ __launch_bounds__(512, 4) void made_main7(
    const int*           __restrict__ state,  // [512]
    const unsigned char* __restrict__ ws,
    const float*         __restrict__ bias,   // [1024]
    float*               __restrict__ out)    // [512, 1024]
{
    __shared__ int   list[BS];
    __shared__ int   cnt;
    __shared__ float red[3][2][16][64];   // [q-1][m][reg][lane] 24 KB

    const int tid  = threadIdx.x;
    const int lane = tid & 63;
    const int w    = tid >> 6;
    const int q    = w & 3;               // K-quarter
    const int m    = w >> 2;              // m-frag (rows m*32..m*32+31)
    const int s    = blockIdx.x & 15;
    const int ot   = blockIdx.x >> 4;

    if (tid == 0) cnt = 0;
    __syncthreads();
    { int st = state[tid]; if (st == s) { int p = atomicAdd(&cnt, 1); list[p] = tid; } }
    __syncthreads();
    const int ns = cnt;
    if (ns == 0) return;                  // block-uniform

    const int l31 = lane & 31, khl = lane >> 5;
    const int qoff = q ? (16 + 192 * q) : 0;

    // ---- A preload: 13 bf16x8 frags from this lane's gathered x row ----
    int ridx = m * 32 + l31; if (ridx >= ns) ridx = ns - 1;
    const unsigned short* xrow =
        (const unsigned short*)(ws + XT_OFF) + (size_t)list[ridx] * IN_DIM;
    bf16x8 a[13];
#pragma unroll
    for (int t = 0; t < 13; ++t) {
        const int off = (q && t == 12) ? qoff : qoff + t * 16;  // pad-safe
        a[t] = *(const bf16x8*)(xrow + off + khl * 8);
    }

    // ---- K-loop: coalesced kern frag + bit-expand, no barriers ----
    const uint4* kp = (const uint4*)(ws + KQ_OFF) + ((size_t)(ot * 4 + q) * 13) * 64 + lane;
    const unsigned char* bp = ws + MB_OFF + (((size_t)(s * 32 + ot) * 4 + q) * 13) * 64 + lane;

    f32x16 acc;
#pragma unroll
    for (int r = 0; r < 16; ++r) acc[r] = 0.f;

#pragma unroll
    for (int t = 0; t < 13; ++t) {
        uint4 kv = kp[t * 64];
        unsigned bb = bp[t * 64];
        uint4 bv;
        bv.x = kv.x & ((bb &   1u ? 0xFFFFu : 0u) | (bb &   2u ? 0xFFFF0000u : 0u));
        bv.y = kv.y & ((bb &   4u ? 0xFFFFu : 0u) | (bb &   8u ? 0xFFFF0000u : 0u));
        bv.z = kv.z & ((bb &  16u ? 0xFFFFu : 0u) | (bb &  32u ? 0xFFFF0000u : 0u));
        bv.w = kv.w & ((bb &  64u ? 0xFFFFu : 0u) | (bb & 128u ? 0xFFFF0000u : 0u));
        bf16x8 bfr; __builtin_memcpy(&bfr, &bv, 16);
        acc = __builtin_amdgcn_mfma_f32_32x32x16_bf16(a[t], bfr, acc, 0, 0, 0);
    }

    // ---- reduce 4 K-quarters, fused bias+relu store ----
    if (q) {
#pragma unroll
        for (int j = 0; j < 16; ++j) red[q - 1][m][j][lane] = acc[j];
    }
    __syncthreads();
    if (q == 0) {
        const float bv = bias[ot * 32 + l31];
#pragma unroll
        for (int j = 0; j < 16; ++j) {
            float v = acc[j] + red[0][m][j][lane] + red[1][m][j][lane] + red[2][m][j][lane];
            const int row = (j & 3) + 8 * (j >> 2) + 4 * khl;   // C/D layout (m74/m101)
            const int sr  = m * 32 + row;
            if (sr < ns) {
                float o = v + bv;
                out[(size_t)list[sr] * OUT_DIM + ot * 32 + l31] = o > 0.f ? o : 0.f;
            }
        }
    }
}

extern "C" void kernel_launch(void* const* d_in, const int* in_sizes, int n_in,
                              void* d_out, int out_size, void* d_ws, size_t ws_size,
                              hipStream_t stream) {
    (void)in_sizes; (void)n_in; (void)out_size; (void)ws_size;
    const float* x     = (const float*)d_in[0];
    const int*   state = (const int*)  d_in[1];
    const float* masks = (const float*)d_in[2];
    const float* kern  = (const float*)d_in[3];
    const float* b0    = (const float*)d_in[4];
    float* out = (float*)d_out;
    unsigned char* ws = (unsigned char*)d_ws;

    made_pre7<<<dim3(NMASK_BLOCKS + NKERN_BLOCKS + NXT_BLOCKS + NPAD_BLOCKS),
                dim3(256), 0, stream>>>(x, masks, kern, ws);
    made_main7<<<dim3(512), dim3(512), 0, stream>>>(state, ws, b0, out);
}